// Round 7
// baseline (141.056 us; speedup 1.0000x reference)
//
#include <hip/hip_runtime.h>
#include <math.h>
#include <stdint.h>

#define ALPHA 0.2f

typedef __attribute__((ext_vector_type(8)))  short bf16x8;
typedef __attribute__((ext_vector_type(4)))  float f32x4;
typedef __attribute__((ext_vector_type(16))) float f32x16;

__device__ __forceinline__ uint32_t pack_bf16(float a, float b) {
    return ((__float_as_uint(a) + 0x8000u) >> 16) |
           ((__float_as_uint(b) + 0x8000u) & 0xFFFF0000u);
}

// ---------------------------------------------------------------------------
// Kernel 1: k_pre — fused k_wh + k_adjb (block-branched grid). Verified
// passing (rounds 3-6). Do not touch this round.
// ---------------------------------------------------------------------------
__global__ __launch_bounds__(512) void k_pre(const float* __restrict__ x,
                                             const float* __restrict__ W,
                                             const float* __restrict__ a,
                                             const float* __restrict__ adj,
                                             uint4* __restrict__ Whf,
                                             float* __restrict__ Wh1,
                                             float* __restrict__ Wh2,
                                             unsigned char* __restrict__ adjq) {
    __shared__ float xs[16 * 512];        // 32 KB
    __shared__ float Wv[128 * 68];        // 34.8 KB

    if (blockIdx.x >= 512) {
        // ---- adjb part: 256 blocks x 512 threads, idx 0..131071 ----
        int idx = (blockIdx.x - 512) * 512 + threadIdx.x;
        int i   = idx >> 7;
        int pos = idx & 127;                            // jg
        const float4* a4 = (const float4*)adj + idx * 2;
        float4 v0 = a4[0], v1 = a4[1];
        unsigned int by = 0;
        by |= (v0.x > 0.f) ? 1u : 0u;
        by |= (v0.y > 0.f) ? 2u : 0u;
        by |= (v0.z > 0.f) ? 4u : 0u;
        by |= (v0.w > 0.f) ? 8u : 0u;
        by |= (v1.x > 0.f) ? 16u : 0u;
        by |= (v1.y > 0.f) ? 32u : 0u;
        by |= (v1.z > 0.f) ? 64u : 0u;
        by |= (v1.w > 0.f) ? 128u : 0u;
        adjq[(i << 7) + ((pos & 1) << 6) + (((pos >> 1) & 1) << 5) + (pos >> 2)] =
            (unsigned char)by;
        return;
    }

    // ---- wh part ----
    const int tid = threadIdx.x;
    const int b   = blockIdx.x & 7;
    const int jt  = blockIdx.x >> 3;      // 0..63 (16-row tiles)

    const float4* xg4 = (const float4*)(x + (size_t)(b * 1024 + jt * 16) * 512);
    #pragma unroll
    for (int i = 0; i < 4; ++i) {
        int    idx = tid + i * 512;       // 0..2047
        float4 v   = xg4[idx];
        int jl  = idx >> 7;
        int rem = idx & 127;
        int f   = rem >> 1;
        int tq  = rem & 1;
        int kk  = f ^ ((jl >> 2) << 2);
        float* dst = &xs[jl * 512 + (tq * 4) * 64 + kk];
        dst[0]   = v.x;
        dst[64]  = v.y;
        dst[128] = v.z;
        dst[192] = v.w;
    }
    const float4* Wg4 = (const float4*)W;
    #pragma unroll
    for (int i = 0; i < 4; ++i) {
        int    idx = tid + i * 512;       // 0..2047
        float4 v   = Wg4[idx];
        int k  = idx >> 5;
        int o0 = (idx & 31) * 4;
        #pragma unroll
        for (int c = 0; c < 4; ++c) {
            int o   = o0 + c;
            int adr = o * 68 + ((((k >> 2) ^ ((o >> 3) & 7)) << 2) | (k & 3));
            Wv[adr] = (&v.x)[c];
        }
    }
    __syncthreads();

    const int w  = tid >> 6;              // wave = t (0..7)
    const int l  = tid & 63;
    const int q  = l >> 4;
    const int om = l & 15;
    const int t  = w;

    float acc[4][8];
    #pragma unroll
    for (int jj = 0; jj < 4; ++jj)
        #pragma unroll
        for (int nt = 0; nt < 8; ++nt) acc[jj][nt] = 0.f;

    for (int kc = 0; kc < 64; kc += 4) {
        float4 xv[4], wv[8];
        const int kx = kc ^ (q << 2);
        #pragma unroll
        for (int jj = 0; jj < 4; ++jj)
            xv[jj] = *(const float4*)&xs[(q * 4 + jj) * 512 + t * 64 + kx];
        #pragma unroll
        for (int nt = 0; nt < 8; ++nt) {
            int og  = nt * 16 + om;
            int grp = (kc >> 2) ^ ((nt * 2 + (om >> 3)) & 7);
            wv[nt]  = *(const float4*)&Wv[og * 68 + grp * 4];
        }
        #pragma unroll
        for (int jj = 0; jj < 4; ++jj) {
            #pragma unroll
            for (int nt = 0; nt < 8; ++nt) {
                float s = acc[jj][nt];
                s = fmaf(xv[jj].x, wv[nt].x, s);
                s = fmaf(xv[jj].y, wv[nt].y, s);
                s = fmaf(xv[jj].z, wv[nt].z, s);
                s = fmaf(xv[jj].w, wv[nt].w, s);
                acc[jj][nt] = s;
            }
        }
    }

    const int bt = b * 8 + t;

    float a1v[8], a2v[8];
    #pragma unroll
    for (int nt = 0; nt < 8; ++nt) {
        a1v[nt] = a[nt * 16 + om];
        a2v[nt] = a[128 + nt * 16 + om];
    }
    #pragma unroll
    for (int jj = 0; jj < 4; ++jj) {
        float s1 = 0.f, s2 = 0.f;
        #pragma unroll
        for (int nt = 0; nt < 8; ++nt) {
            s1 = fmaf(acc[jj][nt], a1v[nt], s1);
            s2 = fmaf(acc[jj][nt], a2v[nt], s2);
        }
        #pragma unroll
        for (int off = 1; off < 16; off <<= 1) {
            s1 += __shfl_xor(s1, off);
            s2 += __shfl_xor(s2, off);
        }
        if (om == 0) {
            int j = jt * 16 + q * 4 + jj;
            Wh1[bt * 1024 + j] = s1;
            Wh2[bt * 1024 + j] = s2;
        }
    }

    // 32x32x16 B-frag store
    #pragma unroll
    for (int nt = 0; nt < 8; ++nt) {
        uint2 st;
        st.x = pack_bf16(acc[0][nt], acc[1][nt]);
        st.y = pack_bf16(acc[2][nt], acc[3][nt]);
        int    lane2 = ((q >> 1) << 5) | ((nt & 1) << 4) | om;
        size_t fidx  = ((size_t)(bt * 4 + (nt >> 1)) * 64 + jt) * 64 + lane2;
        char*  p     = (char*)(Whf + fidx) + ((q & 1) << 3);
        *(uint2*)p = st;
    }
}

// ---------------------------------------------------------------------------
// Kernel 2: k_agg — ROUND-16: occupancy push on the proven structure.
//   Round-6 counters: Occ 16.9%, Mfma 15%, VALU 31%, HBM 10% at 52 us —
//   latency-bound; LDS 74.75 KB -> only 2 blocks/CU (2 waves/SIMD), so
//   barrier drains and LDS-read chains have nothing to hide behind.
//   Change: supersteps 8x128j -> 16x64j. bstage[2][2048] -> [2][1024]
//   (64->32 KB), pf[8] -> pf[4] (register pressure DROPS). LDS ~41 KB ->
//   3 blocks/CU = 12 waves (+50% independent work). Barriers 8 -> 16, but
//   each syncs half the work and 2 other blocks cover each drain.
//   wh1s LDS round-trip replaced by direct per-thread Wh1 load.
//   Index remap (derived from round-0 verified layout):
//     kf = v*4+f  (== old u*8+ts_old)
//     pe = (ts&1)*32 + (v>>1)*4 + (v&1)*2 + (ts>>1)
//     jb = v*64 + ts*16 + g*8
//   Register-pressure history (DO NOT re-litigate): launch-bounds minima
//   and gload_lds variants all spilled (r10/r12/r13/r14). 88 VGPR is the
//   working point; pf-reg + ds_write staging is the only non-spilling form.
// Layouts: A idx=lane&31, k=(lane>>5)*8+e; D col=lane&31,
// row=(reg&3)+8*(reg>>2)+4*(lane>>5); l_i via ones-MFMA.
// Grid 512: blockIdx = ((itile*8 + t)*8 + b) -> XCD = b (matches k_pre's
// writer XCD -> planes are L2-local).
// ---------------------------------------------------------------------------
__global__ __launch_bounds__(256) void k_agg(const uint4* __restrict__ Whf,
                                             const float* __restrict__ Wh1,
                                             const float* __restrict__ Wh2,
                                             const unsigned char* __restrict__ adjq,
                                             float* __restrict__ out) {
    __shared__ __attribute__((aligned(16))) uint4 bstage[2][1024];  // 32 KB
    __shared__ __attribute__((aligned(16))) float efsE[1024];       // 4 KB
    __shared__ __attribute__((aligned(16))) float efsF[1024];       // 4 KB
    __shared__ float m2s[4];

    const int tid   = threadIdx.x;
    const int b     = blockIdx.x & 7;
    const int t     = (blockIdx.x >> 3) & 7;
    const int itile = blockIdx.x >> 6;            // 0..7
    const int bt    = b * 8 + t;
    const int i0    = itile * 128;

    const int w   = tid >> 6;                     // wave 0..3 (= ntile chunk)
    const int l   = tid & 63;
    const int col = l & 31;
    const int g   = l >> 5;                       // k-half group
    const int row = w * 32 + col;                 // block-local i-row

    const uint4* plane = Whf + (size_t)bt * 16384;

    // prefetch superstep 0 (kf 0..3 of this wave's ntile chunk)
    uint4 pf[4];
    #pragma unroll
    for (int f = 0; f < 4; ++f) pf[f] = plane[(w * 64 + f) * 64 + l];

    // adj mask regs: 64 B at (i0+row)*128 + g*64
    const uint4* ap = (const uint4*)(adjq + ((size_t)(i0 + row) << 7) + (g << 6));
    uint4 am[4];
    #pragma unroll
    for (int f = 0; f < 4; ++f) am[f] = ap[f];

    // stage E/F (separate fp32) + running max of h2; h1 direct per-thread
    const float* wh2g = Wh2 + bt * 1024;
    float mx = -1e30f;
    #pragma unroll
    for (int rep = 0; rep < 4; ++rep) {
        int   j  = tid + rep * 256;
        float h2 = wh2g[j];
        efsE[j] = __expf(h2);
        efsF[j] = __expf(ALPHA * h2);
        mx = fmaxf(mx, h2);
    }
    #pragma unroll
    for (int off = 1; off < 64; off <<= 1) mx = fmaxf(mx, __shfl_xor(mx, off));
    if (l == 0) m2s[w] = mx;
    const float h1 = Wh1[bt * 1024 + i0 + row];

    #pragma unroll
    for (int f = 0; f < 4; ++f) bstage[0][(w * 4 + f) * 64 + l] = pf[f];
    __syncthreads();

    const float M2 = fmaxf(fmaxf(m2s[0], m2s[1]), fmaxf(m2s[2], m2s[3]));
    const float e0 = h1 + M2;
    const float mp = fmaxf(e0, ALPHA * e0);       // both products <= 1
    const float Af = __expf(h1 - mp);
    const float Bf = __expf(ALPHA * h1 - mp);

    f32x16 acc[4];
    #pragma unroll
    for (int nt2 = 0; nt2 < 4; ++nt2)
        #pragma unroll
        for (int r = 0; r < 16; ++r) acc[nt2][r] = 0.f;
    f32x16 accl;
    #pragma unroll
    for (int r = 0; r < 16; ++r) accl[r] = 0.f;

    bf16x8 ones;
    #pragma unroll
    for (int i = 0; i < 8; ++i) ones[i] = (short)0x3F80;

    #pragma unroll
    for (int v = 0; v < 16; ++v) {
        if (v + 1 < 16) {
            #pragma unroll
            for (int f = 0; f < 4; ++f)
                pf[f] = plane[(w * 64 + (v + 1) * 4 + f) * 64 + l];
        }

        #pragma unroll
        for (int ts = 0; ts < 4; ++ts) {          // 16-j MFMA slice
            const int jb = v * 64 + ts * 16 + g * 8;
            float4 E0 = *(const float4*)&efsE[jb];
            float4 E1 = *(const float4*)&efsE[jb + 4];
            float4 F0 = *(const float4*)&efsF[jb];
            float4 F1 = *(const float4*)&efsF[jb + 4];

            // adj byte (static select after full unroll)
            const int      pe = (ts & 1) * 32 + (v >> 1) * 4 + (v & 1) * 2 + (ts >> 1);
            const uint4    av = am[pe >> 4];
            const int      cc = (pe >> 2) & 3;
            const uint32_t cw = (cc == 0) ? av.x : (cc == 1) ? av.y
                               : (cc == 2) ? av.z : av.w;
            const uint32_t by = (cw >> ((pe & 3) * 8)) & 0xFFu;

            float p[8];
            p[0] = fmaxf(Af * E0.x, Bf * F0.x) * (float)((by >> 0) & 1u);
            p[1] = fmaxf(Af * E0.y, Bf * F0.y) * (float)((by >> 1) & 1u);
            p[2] = fmaxf(Af * E0.z, Bf * F0.z) * (float)((by >> 2) & 1u);
            p[3] = fmaxf(Af * E0.w, Bf * F0.w) * (float)((by >> 3) & 1u);
            p[4] = fmaxf(Af * E1.x, Bf * F1.x) * (float)((by >> 4) & 1u);
            p[5] = fmaxf(Af * E1.y, Bf * F1.y) * (float)((by >> 5) & 1u);
            p[6] = fmaxf(Af * E1.z, Bf * F1.z) * (float)((by >> 6) & 1u);
            p[7] = fmaxf(Af * E1.w, Bf * F1.w) * (float)((by >> 7) & 1u);

            union { uint32_t u32[4]; bf16x8 v8; } pk;
            #pragma unroll
            for (int r = 0; r < 4; ++r)
                pk.u32[r] = pack_bf16(p[2 * r], p[2 * r + 1]);

            #pragma unroll
            for (int nt2 = 0; nt2 < 4; ++nt2) {
                union { uint4 u4; bf16x8 v8; } br;
                br.u4 = bstage[v & 1][(nt2 * 4 + ts) * 64 + l];
                acc[nt2] = __builtin_amdgcn_mfma_f32_32x32x16_bf16(
                    pk.v8, br.v8, acc[nt2], 0, 0, 0);
            }
            accl = __builtin_amdgcn_mfma_f32_32x32x16_bf16(
                pk.v8, ones, accl, 0, 0, 0);
        }

        if (v + 1 < 16) {
            #pragma unroll
            for (int f = 0; f < 4; ++f)
                bstage[(v + 1) & 1][(w * 4 + f) * 64 + l] = pf[f];
        }
        __syncthreads();
    }

    // epilogue: D rows r = (reg&3)+8*(reg>>2)+4*g; accl rows identical
    float* og = out + ((size_t)(b * 1024 + i0 + w * 32)) * 1024 + t;
    #pragma unroll
    for (int reg = 0; reg < 16; ++reg) {
        const int   r    = (reg & 3) + 8 * (reg >> 2) + 4 * g;
        const float linv = 1.0f / accl[reg];
        #pragma unroll
        for (int nt2 = 0; nt2 < 4; ++nt2) {
            float vv = acc[nt2][reg] * linv;
            vv = vv > 0.f ? vv : __expf(vv) - 1.f;
            og[(size_t)r * 1024 + (nt2 * 32 + col) * 8] = vv;
        }
    }
}

// ---------------------------------------------------------------------------
extern "C" void kernel_launch(void* const* d_in, const int* in_sizes, int n_in,
                              void* d_out, int out_size, void* d_ws, size_t ws_size,
                              hipStream_t stream) {
    const float* x   = (const float*)d_in[0];   // (8,1024,64,8)
    const float* adj = (const float*)d_in[1];   // (1024,1024)
    const float* W   = (const float*)d_in[2];   // (64,128)
    const float* a   = (const float*)d_in[3];   // (256,1)
    float* out = (float*)d_out;                 // (8,1024,128,8)

    uint4*         Whf  = (uint4*)d_ws;                        // 1048576 uint4 = 16 MB
    float*         Wh1  = (float*)(Whf + 1048576);             // 65536 f
    float*         Wh2  = Wh1 + 65536;                         // 65536 f
    unsigned char* adjq = (unsigned char*)(Wh2 + 65536);       // 131072 B

    k_pre<<<768, 512, 0, stream>>>(x, W, a, adj, Whf, Wh1, Wh2, adjq);
    k_agg<<<512, 256, 0, stream>>>(Whf, Wh1, Wh2, adjq, out);
}